// Round 1
// baseline (926.814 us; speedup 1.0000x reference)
//
#include <hip/hip_runtime.h>

#define NEGV -1e30f

// logaddexp matching jnp semantics for our value ranges:
// m + log(1 + exp(min - m)); d <= 0 always, exp never overflows.
__device__ __forceinline__ float lae(float a, float b) {
    float m = fmaxf(a, b);
    float d = fminf(a, b) - m;
    return m + __logf(1.0f + __expf(d));
}

// Output 1: log_prob_matrix = log(probs + 1e-30), written to d_out+1 (flat).
__global__ void log_matrix_kernel(const float* __restrict__ p,
                                  float* __restrict__ out, int n4) {
    int i = blockIdx.x * blockDim.x + threadIdx.x;
    if (i >= n4) return;
    const float4 v = ((const float4*)p)[i];
    int base = i * 4;
    // out is d_out+1 (4B-misaligned for float4) -> scalar stores
    out[base + 0] = logf(v.x + 1e-30f);
    out[base + 1] = logf(v.y + 1e-30f);
    out[base + 2] = logf(v.z + 1e-30f);
    out[base + 3] = logf(v.w + 1e-30f);
}

// DP: one wave (64 lanes) per batch b; lane owns l = lane*4 .. lane*4+3.
// alpha[t,l] = logaddexp(alpha[t-1,l], alpha[t-1,l-1]) + log(probs[b,l,t]+1e-30)
// Cross-lane dependency handled with a single shfl_up of the lane's top value.
__global__ void dp_kernel(const float* __restrict__ probs,
                          const int* __restrict__ text_len,
                          const int* __restrict__ mel_len,
                          float* __restrict__ alpha_out,
                          int L, int T) {
    const int b = blockIdx.x;
    const int lane = threadIdx.x;  // 0..63
    const float* pb = probs + (size_t)b * L * T;
    const int tl = text_len[b];
    const int ml = mel_len[b];

    const float* r0 = pb + (size_t)(lane * 4 + 0) * T;
    const float* r1 = r0 + T;
    const float* r2 = r1 + T;
    const float* r3 = r2 + T;

    // t = 0: only l == 0 alive
    float a0 = (lane == 0) ? __logf(r0[0] + 1e-30f) : NEGV;
    float a1 = NEGV, a2 = NEGV, a3 = NEGV;

    // software prefetch of the t+1 probs (off the critical alpha chain)
    float c0 = 0.f, c1 = 0.f, c2 = 0.f, c3 = 0.f;
    if (ml > 1) { c0 = r0[1]; c1 = r1[1]; c2 = r2[1]; c3 = r3[1]; }

    for (int t = 1; t < ml; ++t) {
        float n0 = 0.f, n1 = 0.f, n2 = 0.f, n3 = 0.f;
        if (t + 1 < ml) { n0 = r0[t + 1]; n1 = r1[t + 1]; n2 = r2[t + 1]; n3 = r3[t + 1]; }

        float top = __shfl_up(a3, 1, 64);   // previous lane's highest-l alpha
        if (lane == 0) top = NEGV;

        float lp0 = __logf(c0 + 1e-30f);
        float lp1 = __logf(c1 + 1e-30f);
        float lp2 = __logf(c2 + 1e-30f);
        float lp3 = __logf(c3 + 1e-30f);

        float b0 = lae(a0, top) + lp0;
        float b1 = lae(a1, a0) + lp1;
        float b2 = lae(a2, a1) + lp2;
        float b3 = lae(a3, a2) + lp3;

        a0 = b0; a1 = b1; a2 = b2; a3 = b3;
        c0 = n0; c1 = n1; c2 = n2; c3 = n3;
    }

    // capture alpha_last[b] = alpha[mel_len-1][text_len-1]
    const int cl = tl - 1;
    if (lane == (cl >> 2)) {
        const int j = cl & 3;
        float v = (j == 0) ? a0 : (j == 1) ? a1 : (j == 2) ? a2 : a3;
        alpha_out[b] = v;
    }
}

// Output 0: mdn_loss = -mean(alpha_last)
__global__ void loss_kernel(const float* __restrict__ alpha,
                            float* __restrict__ out, int B) {
    float v = alpha[threadIdx.x];
#pragma unroll
    for (int off = 32; off > 0; off >>= 1) v += __shfl_down(v, off, 64);
    if (threadIdx.x == 0) out[0] = -v / (float)B;
}

extern "C" void kernel_launch(void* const* d_in, const int* in_sizes, int n_in,
                              void* d_out, int out_size, void* d_ws, size_t ws_size,
                              hipStream_t stream) {
    const float* probs    = (const float*)d_in[0];
    // d_in[1] = melspec: unused by the reference math (only supplies T)
    const int*   text_len = (const int*)d_in[2];
    const int*   mel_len  = (const int*)d_in[3];
    float* out = (float*)d_out;

    const int B = in_sizes[2];                    // 64
    const int n = in_sizes[0];                    // B*L*T = 26,214,400
    const int T = in_sizes[1] / (B * 80);         // melspec [B,80,T] -> 1600
    const int L = n / (B * T);                    // 256

    // 1) log_prob_matrix -> d_out + 1
    const int n4 = n / 4;
    log_matrix_kernel<<<(n4 + 255) / 256, 256, 0, stream>>>(probs, out + 1, n4);

    // 2) DP scan -> alpha_last per batch in workspace
    dp_kernel<<<B, 64, 0, stream>>>(probs, text_len, mel_len, (float*)d_ws, L, T);

    // 3) loss -> d_out[0]
    loss_kernel<<<1, B, 0, stream>>>((const float*)d_ws, out, B);
}

// Round 2
// 420.567 us; speedup vs baseline: 2.2037x; 2.2037x over previous
//
#include <hip/hip_runtime.h>

#define NEG2  -1.442695e30f                 // -1e30 * log2(e), the log2-domain "dead" value
#define LN2f   0.69314718055994531f

#if __has_builtin(__builtin_amdgcn_exp2f)
#define EXP2(x) __builtin_amdgcn_exp2f(x)
#else
#define EXP2(x) exp2f(x)
#endif
#if __has_builtin(__builtin_amdgcn_logf)
#define LOG2(x) __builtin_amdgcn_logf(x)
#else
#define LOG2(x) log2f(x)
#endif

// Output 1: log_prob_matrix = log(probs + 1e-30) -> d_out+1 (flat).
// Lane-consecutive dword access (out+1 makes float4 stores misaligned).
__global__ __launch_bounds__(256) void log_matrix_kernel(const float* __restrict__ p,
                                                         float* __restrict__ out, int n) {
    int base = blockIdx.x * 1024 + threadIdx.x;
#pragma unroll
    for (int k = 0; k < 4; ++k) {
        int idx = base + k * 256;
        if (idx < n) out[idx] = logf(p[idx] + 1e-30f);
    }
}

// DP: one wave per batch; lane owns l = lane*4 .. lane*4+3 (L=256).
// Works in log2 domain: alpha2 = alpha * log2(e).
// step: a[l] = max2 + log2((1 + 2^(min2-max2)) * (p + 1e-30))
// Deep register pipeline: PD chunks of CK t-steps of float4 loads in flight.
constexpr int CK = 8;   // t-steps per chunk (2 float4 per row)
constexpr int PD = 4;   // chunks in flight -> prefetch distance 32 iters

__global__ __launch_bounds__(64, 1) void dp_kernel(const float* __restrict__ probs,
                                                   const int* __restrict__ text_len,
                                                   const int* __restrict__ mel_len,
                                                   float* __restrict__ alpha_out,
                                                   int L, int T) {
    const int b = blockIdx.x;
    const int lane = threadIdx.x;
    const float* r0 = probs + ((size_t)b * L + lane * 4) * T;
    const float* r1 = r0 + T;
    const float* r2 = r1 + T;
    const float* r3 = r2 + T;
    const int ml1 = mel_len[b] - 1;          // capture time
    const int cl  = text_len[b] - 1;         // capture label
    const bool own = (lane == (cl >> 2));
    const int  jj  = cl & 3;

    float a0 = NEG2, a1 = NEG2, a2 = NEG2, a3 = NEG2;
    float saved = NEG2;

    const int nch  = T / CK;
    const int nchP = (nch / PD) * PD;        // chunks handled by the pipelined loop
    const int tmax = (T >= CK) ? (T - CK) : 0;

    float4 buf[PD][4][2];

    // prologue: chunks 0..PD-1 (clamped; garbage never consumed)
#pragma unroll
    for (int p = 0; p < PD; ++p) {
        int tb = min(p * CK, tmax);
        buf[p][0][0] = *(const float4*)(r0 + tb); buf[p][0][1] = *(const float4*)(r0 + tb + 4);
        buf[p][1][0] = *(const float4*)(r1 + tb); buf[p][1][1] = *(const float4*)(r1 + tb + 4);
        buf[p][2][0] = *(const float4*)(r2 + tb); buf[p][2][1] = *(const float4*)(r2 + tb + 4);
        buf[p][3][0] = *(const float4*)(r3 + tb); buf[p][3][1] = *(const float4*)(r3 + tb + 4);
    }

    for (int kk = 0; kk < nchP; kk += PD) {
#pragma unroll
        for (int p = 0; p < PD; ++p) {
            const int ck = kk + p;
            const int tb = ck * CK;
#pragma unroll
            for (int j = 0; j < CK; ++j) {
                const int q = j >> 2;
                const float4 v0 = buf[p][0][q], v1 = buf[p][1][q],
                             v2 = buf[p][2][q], v3 = buf[p][3][q];
                const float c0 = (j & 3) == 0 ? v0.x : (j & 3) == 1 ? v0.y : (j & 3) == 2 ? v0.z : v0.w;
                const float c1 = (j & 3) == 0 ? v1.x : (j & 3) == 1 ? v1.y : (j & 3) == 2 ? v1.z : v1.w;
                const float c2 = (j & 3) == 0 ? v2.x : (j & 3) == 1 ? v2.y : (j & 3) == 2 ? v2.z : v2.w;
                const float c3 = (j & 3) == 0 ? v3.x : (j & 3) == 1 ? v3.y : (j & 3) == 2 ? v3.z : v3.w;
                const int t = tb + j;
                if (t == 0) {
                    a0 = (lane == 0) ? LOG2(c0 + 1e-30f) : NEG2;
                } else {
                    float top = __shfl_up(a3, 1, 64);
                    if (lane == 0) top = NEG2;
                    float m0 = fmaxf(a0, top), d0 = fminf(a0, top) - m0;
                    float m1 = fmaxf(a1, a0),  d1 = fminf(a1, a0) - m1;
                    float m2 = fmaxf(a2, a1),  d2 = fminf(a2, a1) - m2;
                    float m3 = fmaxf(a3, a2),  d3 = fminf(a3, a2) - m3;
                    float e0 = EXP2(d0), e1 = EXP2(d1), e2 = EXP2(d2), e3 = EXP2(d3);
                    a0 = m0 + LOG2((1.0f + e0) * (c0 + 1e-30f));
                    a1 = m1 + LOG2((1.0f + e1) * (c1 + 1e-30f));
                    a2 = m2 + LOG2((1.0f + e2) * (c2 + 1e-30f));
                    a3 = m3 + LOG2((1.0f + e3) * (c3 + 1e-30f));
                }
                if (t == ml1) {
                    if (own) saved = (jj == 0) ? a0 : (jj == 1) ? a1 : (jj == 2) ? a2 : a3;
                }
            }
            // refill this slot with chunk ck+PD (clamped; unused slots harmless)
            {
                int tb2 = min((ck + PD) * CK, tmax);
                buf[p][0][0] = *(const float4*)(r0 + tb2); buf[p][0][1] = *(const float4*)(r0 + tb2 + 4);
                buf[p][1][0] = *(const float4*)(r1 + tb2); buf[p][1][1] = *(const float4*)(r1 + tb2 + 4);
                buf[p][2][0] = *(const float4*)(r2 + tb2); buf[p][2][1] = *(const float4*)(r2 + tb2 + 4);
                buf[p][3][0] = *(const float4*)(r3 + tb2); buf[p][3][1] = *(const float4*)(r3 + tb2 + 4);
            }
        }
    }

    // epilogue: any t not covered by the pipelined loop (empty when T % (CK*PD) == 0)
    for (int t = nchP * CK; t < T; ++t) {
        const float c0 = r0[t], c1 = r1[t], c2 = r2[t], c3 = r3[t];
        if (t == 0) {
            a0 = (lane == 0) ? LOG2(c0 + 1e-30f) : NEG2;
        } else {
            float top = __shfl_up(a3, 1, 64);
            if (lane == 0) top = NEG2;
            float m0 = fmaxf(a0, top), d0 = fminf(a0, top) - m0;
            float m1 = fmaxf(a1, a0),  d1 = fminf(a1, a0) - m1;
            float m2 = fmaxf(a2, a1),  d2 = fminf(a2, a1) - m2;
            float m3 = fmaxf(a3, a2),  d3 = fminf(a3, a2) - m3;
            float e0 = EXP2(d0), e1 = EXP2(d1), e2 = EXP2(d2), e3 = EXP2(d3);
            a0 = m0 + LOG2((1.0f + e0) * (c0 + 1e-30f));
            a1 = m1 + LOG2((1.0f + e1) * (c1 + 1e-30f));
            a2 = m2 + LOG2((1.0f + e2) * (c2 + 1e-30f));
            a3 = m3 + LOG2((1.0f + e3) * (c3 + 1e-30f));
        }
        if (t == ml1) {
            if (own) saved = (jj == 0) ? a0 : (jj == 1) ? a1 : (jj == 2) ? a2 : a3;
        }
    }

    if (own) alpha_out[b] = saved * LN2f;    // back to natural log
}

// Output 0: mdn_loss = -mean(alpha_last)
__global__ void loss_kernel(const float* __restrict__ alpha,
                            float* __restrict__ out, int B) {
    float v = (threadIdx.x < B) ? alpha[threadIdx.x] : 0.0f;
#pragma unroll
    for (int off = 32; off > 0; off >>= 1) v += __shfl_down(v, off, 64);
    if (threadIdx.x == 0) out[0] = -v / (float)B;
}

extern "C" void kernel_launch(void* const* d_in, const int* in_sizes, int n_in,
                              void* d_out, int out_size, void* d_ws, size_t ws_size,
                              hipStream_t stream) {
    const float* probs    = (const float*)d_in[0];
    // d_in[1] = melspec: unused by the reference math (only supplies T)
    const int*   text_len = (const int*)d_in[2];
    const int*   mel_len  = (const int*)d_in[3];
    float* out = (float*)d_out;

    const int B = in_sizes[2];                    // 64
    const int n = in_sizes[0];                    // B*L*T
    const int T = in_sizes[1] / (B * 80);         // melspec [B,80,T] -> 1600
    const int L = n / (B * T);                    // 256

    // 1) log_prob_matrix -> d_out + 1 (coalesced dword access)
    log_matrix_kernel<<<(n + 1023) / 1024, 256, 0, stream>>>(probs, out + 1, n);

    // 2) DP scan -> alpha_last per batch in workspace
    dp_kernel<<<B, 64, 0, stream>>>(probs, text_len, mel_len, (float*)d_ws, L, T);

    // 3) loss -> d_out[0]
    loss_kernel<<<1, 64, 0, stream>>>((const float*)d_ws, out, B);
}

// Round 3
// 372.948 us; speedup vs baseline: 2.4851x; 1.1277x over previous
//
#include <hip/hip_runtime.h>

#define LN2f 0.69314718055994531f

constexpr int CK   = 8;    // t-steps per chunk (2 float4 per label row)
constexpr int PD   = 4;    // chunks in flight (prefetch distance = 32 steps)
constexpr int DP_B = 64;   // batches == dp blocks
constexpr int T_C  = 1600; // fixed problem shape
constexpr int L_C  = 256;
constexpr int NCH  = T_C / CK;           // 200 chunks
constexpr int NGRP = (NCH - 1 - 3) / 4;  // 49 groups of 4 chunks covering 1..196

// Fused kernel:
//  - blocks [0,64): wave 0 runs the per-batch DP scan (linear domain, per-lane
//    exponent tracking); waves 1..3 join the elementwise log workforce.
//  - blocks [64,G): all 4 waves do log(probs + 1e-30) -> out+1.
__global__ __launch_bounds__(256) void fused_kernel(
    const float* __restrict__ probs,
    const int* __restrict__ text_len,
    const int* __restrict__ mel_len,
    float* __restrict__ out1,       // d_out + 1
    float* __restrict__ alpha_out,  // d_ws, [64]
    int n4, int G)
{
    const int b   = blockIdx.x;
    const int tid = threadIdx.x;

    if (b < DP_B && tid < 64) {
        // ======================= DP path (one wave) =======================
        const int lane = tid;
        const float* rr[4];
        rr[0] = probs + ((size_t)b * L_C + lane * 4) * T_C;
        rr[1] = rr[0] + T_C;
        rr[2] = rr[1] + T_C;
        rr[3] = rr[2] + T_C;
        const int ml1 = mel_len[b] - 1;   // capture time
        const int cl  = text_len[b] - 1;  // capture label

        float a0 = 0.f, a1 = 0.f, a2 = 0.f, a3 = 0.f;  // linear alpha, lane scale 2^E
        int   E = 0;
        bool  alive = (lane == 0);
        float s0 = 0.f, s1 = 0.f, s2 = 0.f, s3 = 0.f;  // captured at t == ml1
        int   sE = 0;

        float4 buf[PD][4][2];

        auto loadc = [&](int slot, int ck) {
            int tb = (ck < NCH - 1 ? ck : NCH - 1) * CK;
#pragma unroll
            for (int r = 0; r < 4; ++r) {
                buf[slot][r][0] = *(const float4*)(rr[r] + tb);
                buf[slot][r][1] = *(const float4*)(rr[r] + tb + 4);
            }
        };

        auto step = [&](float c0, float c1, float c2, float c3, int t) {
            float top = __shfl_up(a3, 1, 64);
            int   tE  = __shfl_up(E, 1, 64);
            top = (lane == 0) ? 0.0f : top;
            float contrib = alive ? ldexpf(top, tE - E) : top;  // rescale to my frame
            E = alive ? E : tE;                                  // adopt sender scale
            alive = alive | (top != 0.0f);
            float n0 = (a0 + contrib) * c0;
            float n1 = (a1 + a0) * c1;
            float n2 = (a2 + a1) * c2;
            float n3 = (a3 + a2) * c3;
            a0 = n0; a1 = n1; a2 = n2; a3 = n3;
            bool cap = (t == ml1);
            s0 = cap ? a0 : s0; s1 = cap ? a1 : s1;
            s2 = cap ? a2 : s2; s3 = cap ? a3 : s3;
            sE = cap ? E : sE;
        };

        auto renorm = [&]() {
            float m = fmaxf(fmaxf(a0, a1), fmaxf(a2, a3));
            int e = ((__float_as_int(m) >> 23) & 255) - 127;
            e = (m > 0.0f) ? e : 0;
            a0 = ldexpf(a0, -e); a1 = ldexpf(a1, -e);
            a2 = ldexpf(a2, -e); a3 = ldexpf(a3, -e);
            E += e;
        };

        auto getc = [&](int slot, int r, int j) -> float {
            const float4 v = buf[slot][r][j >> 2];
            const int q = j & 3;
            return ((q == 0) ? v.x : (q == 1) ? v.y : (q == 2) ? v.z : v.w) + 1e-30f;
        };

#pragma unroll
        for (int sl = 0; sl < PD; ++sl) loadc(sl, sl);

        // ---- chunk 0 (slot 0): t = 0 is the init, then 7 normal steps ----
        {
            a0 = (lane == 0) ? getc(0, 0, 0) : 0.0f;
            if (ml1 == 0) { s0 = a0; s1 = 0.f; s2 = 0.f; s3 = 0.f; sE = 0; }
#pragma unroll
            for (int j = 1; j < CK; ++j)
                step(getc(0, 0, j), getc(0, 1, j), getc(0, 2, j), getc(0, 3, j), j);
            renorm();
            loadc(0, PD);
        }

        // ---- chunks 1..196 in groups of 4 (slots 1,2,3,0) ----
        for (int g = 0; g < NGRP; ++g) {
#pragma unroll
            for (int pp = 0; pp < 4; ++pp) {
                const int  ck   = 1 + g * 4 + pp;
                const int  slot = (1 + pp) & 3;
                const int  tb   = ck * CK;
#pragma unroll
                for (int j = 0; j < CK; ++j)
                    step(getc(slot, 0, j), getc(slot, 1, j),
                         getc(slot, 2, j), getc(slot, 3, j), tb + j);
                renorm();
                loadc(slot, ck + PD);
            }
        }

        // ---- epilogue chunks 197,198,199 (slots 1,2,3) ----
#pragma unroll
        for (int pp = 0; pp < 3; ++pp) {
            const int ck   = NCH - 3 + pp;       // 197+pp
            const int slot = (1 + pp) & 3;       // (197+pp)&3 == (1+pp)&3
            const int tb   = ck * CK;
#pragma unroll
            for (int j = 0; j < CK; ++j)
                step(getc(slot, 0, j), getc(slot, 1, j),
                     getc(slot, 2, j), getc(slot, 3, j), tb + j);
            renorm();
        }

        if (lane == (cl >> 2)) {
            const int jj = cl & 3;
            float v = (jj == 0) ? s0 : (jj == 1) ? s1 : (jj == 2) ? s2 : s3;
            v = fmaxf(v, 1e-44f);
            float res = (log2f(v) + (float)sE) * LN2f;
            alpha_out[b] = (cl > ml1) ? -1e30f : res;
        }
        return;
    }

    // ======================= log path =======================
    // worker index over all non-dp waves
    int widx;
    if (b < DP_B) widx = b * 192 + (tid - 64);
    else          widx = DP_B * 192 + (b - DP_B) * 256 + tid;
    const int W = DP_B * 192 + (G - DP_B) * 256;

    for (int i = widx; i < n4; i += W) {
        const float4 v = ((const float4*)probs)[i];
        const int o = 4 * i;
        out1[o + 0] = logf(v.x + 1e-30f);
        out1[o + 1] = logf(v.y + 1e-30f);
        out1[o + 2] = logf(v.z + 1e-30f);
        out1[o + 3] = logf(v.w + 1e-30f);
    }
}

// Output 0: mdn_loss = -mean(alpha_last)
__global__ void loss_kernel(const float* __restrict__ alpha,
                            float* __restrict__ out, int B) {
    float v = (threadIdx.x < B) ? alpha[threadIdx.x] : 0.0f;
#pragma unroll
    for (int off = 32; off > 0; off >>= 1) v += __shfl_down(v, off, 64);
    if (threadIdx.x == 0) out[0] = -v / (float)B;
}

extern "C" void kernel_launch(void* const* d_in, const int* in_sizes, int n_in,
                              void* d_out, int out_size, void* d_ws, size_t ws_size,
                              hipStream_t stream) {
    const float* probs    = (const float*)d_in[0];
    // d_in[1] = melspec: unused by the reference math (only supplies T)
    const int*   text_len = (const int*)d_in[2];
    const int*   mel_len  = (const int*)d_in[3];
    float* out = (float*)d_out;

    const int B  = in_sizes[2];     // 64
    const int n  = in_sizes[0];     // B*L*T = 26,214,400
    const int n4 = n / 4;
    const int G  = 1024;

    fused_kernel<<<G, 256, 0, stream>>>(probs, text_len, mel_len,
                                        out + 1, (float*)d_ws, n4, G);
    loss_kernel<<<1, 64, 0, stream>>>((const float*)d_ws, out, B);
}

// Round 4
// 312.687 us; speedup vs baseline: 2.9640x; 1.1927x over previous
//
#include <hip/hip_runtime.h>

#define LN2f 0.69314718055994531f

constexpr int CK   = 8;    // t-steps per chunk (2 float4 per label row)
constexpr int PD   = 3;    // chunks in flight (prefetch distance = 24 steps)
constexpr int DP_B = 64;   // batches == dp blocks
constexpr int T_C  = 1600; // fixed problem shape
constexpr int L_C  = 256;
constexpr int NCH  = T_C / CK;   // 200 chunks

// Fused kernel:
//  - blocks [0,64): wave 0 runs the per-batch DP scan at s_setprio 3 (linear
//    domain, per-lane exponent tracking); waves 1..3 join the log workforce.
//  - blocks [64,G): all 4 waves do log(probs + 1e-30) -> out+1.
__global__ __launch_bounds__(256, 1) void fused_kernel(
    const float* __restrict__ probs,
    const int* __restrict__ text_len,
    const int* __restrict__ mel_len,
    float* __restrict__ out1,       // d_out + 1
    float* __restrict__ alpha_out,  // d_ws, [64]
    int n4, int G)
{
    const int b   = blockIdx.x;
    const int tid = threadIdx.x;

    if (b < DP_B && tid < 64) {
        // ======================= DP path (one wave) =======================
        asm volatile("s_setprio 3");   // win issue arbitration vs log waves
        const int lane = tid;
        const float* rr[4];
        rr[0] = probs + ((size_t)b * L_C + lane * 4) * T_C;
        rr[1] = rr[0] + T_C;
        rr[2] = rr[1] + T_C;
        rr[3] = rr[2] + T_C;
        const int ml1 = mel_len[b] - 1;   // capture time
        const int cl  = text_len[b] - 1;  // capture label

        float a0 = 0.f, a1 = 0.f, a2 = 0.f, a3 = 0.f;  // linear alpha, scale 2^E
        int   E = 0;
        bool  alive = (lane == 0);
        float s0 = 0.f, s1 = 0.f, s2 = 0.f, s3 = 0.f;  // captured at t == ml1
        int   sE = 0;

        float4 buf[PD][4][2];   // 96 VGPRs

        auto loadc = [&](int slot, int ck) {
            int tb = ck * CK;
#pragma unroll
            for (int r = 0; r < 4; ++r) {
                buf[slot][r][0] = *(const float4*)(rr[r] + tb);
                buf[slot][r][1] = *(const float4*)(rr[r] + tb + 4);
            }
        };

        auto getc = [&](int slot, int r, int j) -> float {
            const float4 v = buf[slot][r][j >> 2];
            const int q = j & 3;
            return ((q == 0) ? v.x : (q == 1) ? v.y : (q == 2) ? v.z : v.w) + 1e-30f;
        };

        auto step_full = [&](float c0, float c1, float c2, float c3, int t) {
            float top = __shfl_up(a3, 1, 64);
            int   tE  = __shfl_up(E, 1, 64);
            top = (lane == 0) ? 0.0f : top;
            float contrib = alive ? ldexpf(top, tE - E) : top;
            E = alive ? E : tE;
            alive = alive | (top != 0.0f);
            float n0 = (a0 + contrib) * c0;
            float n1 = (a1 + a0) * c1;
            float n2 = (a2 + a1) * c2;
            float n3 = (a3 + a2) * c3;
            a0 = n0; a1 = n1; a2 = n2; a3 = n3;
            if (t == ml1) { s0 = a0; s1 = a1; s2 = a2; s3 = a3; sE = E; }
        };

        auto renorm = [&]() {
            float m = fmaxf(fmaxf(a0, a1), fmaxf(a2, a3));
            int e = ((__float_as_int(m) >> 23) & 255) - 127;
            e = (m > 0.0f) ? e : 0;
            a0 = ldexpf(a0, -e); a1 = ldexpf(a1, -e);
            a2 = ldexpf(a2, -e); a3 = ldexpf(a3, -e);
            E += e;
        };

        auto proc_full = [&](int slot, int ck) {
            const int tb = ck * CK;
#pragma unroll
            for (int j = 0; j < CK; ++j)
                step_full(getc(slot, 0, j), getc(slot, 1, j),
                          getc(slot, 2, j), getc(slot, 3, j), tb + j);
            renorm();
            loadc(slot, ck + PD);   // ck <= 32 here, ck+PD < NCH always
        };

        auto proc_fast = [&](int slot, int ck) {
            // all lanes alive; E constant within chunk -> hoist the E shfl
            int tE = __shfl_up(E, 1, 64);
            int dE = tE - E;
            const int tb = ck * CK;
#pragma unroll
            for (int j = 0; j < CK; ++j) {
                const float c0 = getc(slot, 0, j), c1 = getc(slot, 1, j);
                const float c2 = getc(slot, 2, j), c3 = getc(slot, 3, j);
                float top = __shfl_up(a3, 1, 64);
                top = (lane == 0) ? 0.0f : top;
                float contrib = ldexpf(top, dE);
                float n0 = (a0 + contrib) * c0;
                float n1 = (a1 + a0) * c1;
                float n2 = (a2 + a1) * c2;
                float n3 = (a3 + a2) * c3;
                a0 = n0; a1 = n1; a2 = n2; a3 = n3;
                if (tb + j == ml1) { s0 = a0; s1 = a1; s2 = a2; s3 = a3; sE = E; }
            }
            renorm();
            if (ck + PD < NCH) loadc(slot, ck + PD);
        };

        // prologue: chunks 0,1,2 -> slots 0,1,2
        loadc(0, 0); loadc(1, 1); loadc(2, 2);

        // ---- chunk 0 (slot 0): t = 0 init, then 7 full steps ----
        {
            a0 = (lane == 0) ? getc(0, 0, 0) : 0.0f;
            if (ml1 == 0) { s0 = a0; s1 = 0.f; s2 = 0.f; s3 = 0.f; sE = 0; }
#pragma unroll
            for (int j = 1; j < CK; ++j)
                step_full(getc(0, 0, j), getc(0, 1, j), getc(0, 2, j), getc(0, 3, j), j);
            renorm();
            loadc(0, PD);
        }

        // ---- full-machinery chunks 1..32 (t < 264; aliveness frontier) ----
        for (int g = 0; g < 10; ++g) {
            const int ck = 1 + 3 * g;
            proc_full(1, ck); proc_full(2, ck + 1); proc_full(0, ck + 2);
        }
        proc_full(1, 31);
        proc_full(2, 32);

        // ---- streamlined chunks 33..199 (all labels alive) ----
        for (int g = 0; g < 55; ++g) {
            const int ck = 33 + 3 * g;
            proc_fast(0, ck); proc_fast(1, ck + 1); proc_fast(2, ck + 2);
        }
        proc_fast(0, 198);
        proc_fast(1, 199);

        if (lane == (cl >> 2)) {
            const int jj = cl & 3;
            float v = (jj == 0) ? s0 : (jj == 1) ? s1 : (jj == 2) ? s2 : s3;
            v = fmaxf(v, 1e-44f);
            float res = (log2f(v) + (float)sE) * LN2f;
            alpha_out[b] = (cl > ml1) ? -1e30f : res;
        }
        return;
    }

    // ======================= log path =======================
    int widx;
    if (b < DP_B) widx = b * 192 + (tid - 64);
    else          widx = DP_B * 192 + (b - DP_B) * 256 + tid;
    const int W = DP_B * 192 + (G - DP_B) * 256;

    for (int i = widx; i < n4; i += W) {
        const float4 v = ((const float4*)probs)[i];
        const int o = 4 * i;
        out1[o + 0] = logf(v.x + 1e-30f);
        out1[o + 1] = logf(v.y + 1e-30f);
        out1[o + 2] = logf(v.z + 1e-30f);
        out1[o + 3] = logf(v.w + 1e-30f);
    }
}

// Output 0: mdn_loss = -mean(alpha_last)
__global__ void loss_kernel(const float* __restrict__ alpha,
                            float* __restrict__ out, int B) {
    float v = (threadIdx.x < B) ? alpha[threadIdx.x] : 0.0f;
#pragma unroll
    for (int off = 32; off > 0; off >>= 1) v += __shfl_down(v, off, 64);
    if (threadIdx.x == 0) out[0] = -v / (float)B;
}

extern "C" void kernel_launch(void* const* d_in, const int* in_sizes, int n_in,
                              void* d_out, int out_size, void* d_ws, size_t ws_size,
                              hipStream_t stream) {
    const float* probs    = (const float*)d_in[0];
    // d_in[1] = melspec: unused by the reference math (only supplies T)
    const int*   text_len = (const int*)d_in[2];
    const int*   mel_len  = (const int*)d_in[3];
    float* out = (float*)d_out;

    const int B  = in_sizes[2];     // 64
    const int n  = in_sizes[0];     // B*L*T = 26,214,400
    const int n4 = n / 4;
    const int G  = 1024;

    fused_kernel<<<G, 256, 0, stream>>>(probs, text_len, mel_len,
                                        out + 1, (float*)d_ws, n4, G);
    loss_kernel<<<1, 64, 0, stream>>>((const float*)d_ws, out, B);
}